// Round 3
// baseline (174.516 us; speedup 1.0000x reference)
//
#include <hip/hip_runtime.h>
#include <hip/hip_bf16.h>
#include <hip/hip_fp16.h>

// GeneratorSDF: latent-conditioned MLP SDF on a 128^3 grid (fp32 I/O).
// dims: 67 -> 128 -> 64 -> 32 -> 1 (relu, relu, relu, sigmoid)
//
// R25 = R22 (best verified: 53.5us) + occupancy 2->3 waves/SIMD.
// Post-mortem R23/R24: permlane variants added ~3.5us VALU and runtime rose
// 1:1; pipelining recovered nothing. Cycle model: demand/iter is ~390 MFMA-cyc
// + ~160 VALU-cyc per SIMD but observed ~1000 cyc/iter -> LATENCY-bound with
// only 2 waves/SIMD of TLP (unified-file cap: 80 AGPR a2/a3 + ~100 VGPR).
// Fix: demote 32 regs of loop-invariant constants that already live in LDS
// (b2q 16, b3q 8, w4 8) to per-iteration VOLATILE broadcast ds_read_b128
// (LDS pipe, not VALU; volatile blocks hoist-back). That clears the ~12-reg
// overshoot that made the prior session's (256,3) spill (R15/R16), so
// __launch_bounds__(256,3) now fits spill-free and guarantees 3 waves/SIMD.
// VALU per iteration is UNCHANGED vs R22 (the R23/R24 lesson: every added
// VALU instr costs ~1:1 here). Everything else is byte-identical R22:
// fp16 datapath, h2 LDS double-buffer + b3f prefetch, batched cphase,
// pinned twp/tbp, jrow-outer 4x8, 4-way-parallel W1 fold, grid 1024.
// MFMA layouts (verified m89/m91): A[m=lane&15][k=quad*8+j],
// B[k=quad*8+j][n=lane&15], C/D row=quad*4+reg, col=lane&15.

#define NPTS (128 * 128 * 128)

typedef float f32x4_t __attribute__((ext_vector_type(4)));
typedef float f32x2_t __attribute__((ext_vector_type(2)));
typedef __fp16 g16x2_t __attribute__((ext_vector_type(2)));    // VALU half2 (cvt_pkrtz type)
typedef _Float16 h16x8_t __attribute__((ext_vector_type(8)));  // MFMA fragment

__device__ __forceinline__ unsigned h2u(g16x2_t h) {
    unsigned u;
    __builtin_memcpy(&u, &h, 4);
    return u;
}
__device__ __forceinline__ g16x2_t u2h(unsigned u) {
    g16x2_t h;
    __builtin_memcpy(&h, &u, 4);
    return h;
}
// Volatile LDS vector load: emitted per call site, cannot be hoisted into a
// loop-invariant register (that's the point -- frees 32 persistent VGPRs).
__device__ __forceinline__ f32x4_t ldsv4(const float* p) {
    return *(const volatile f32x4_t*)p;
}

__global__ __launch_bounds__(256, 3) void mlp_kernel(
    const float* __restrict__ x,  const float* __restrict__ W1,
    const float* __restrict__ b1, const float* __restrict__ W2,
    const float* __restrict__ b2, const float* __restrict__ W3,
    const float* __restrict__ b3, const float* __restrict__ W4,
    const float* __restrict__ b4, float* __restrict__ out) {
    __shared__ __align__(16) unsigned s_basep[16][64];  // half2 {base[2c],base[2c+1]} per j
    __shared__ __align__(16) unsigned s_wcp[64];        // half2 wc pairs
    __shared__ __align__(16) float s_b2[64];
    __shared__ __align__(16) float s_b3[32];
    __shared__ __align__(16) float s_w4[32];
    // Union (26.6 KB): staging = w2a[16][64][8] halves (0..8191) + w3a[4][64][8]
    // (8192..10239) + W1-fold partials (floats at shorts 10240..11263, transient);
    // runtime = h2 slots [w][2][16][72] (0..9215) + zf floats
    // (shorts 9216..13311 = float[4][8][16][4] : w*512 + pg*64 + i*4 + q).
    __shared__ __align__(16) unsigned short s_u[13312];

    const int t = threadIdx.x;
    const int w = t >> 6;
    const int lane = t & 63;
    const int quad = lane >> 4;
    const int l15 = lane & 15;
    const float step = 2.0f / 127.0f;

    // ================= per-block prep, phase 1 (all 256 threads) =============
    // W1 fold partials: thread covers channel-pair p = t&63, c in [h*16,(h+1)*16)
    {
        const int p = t & 63, h = t >> 6;
        const float* r0 = W1 + (2 * p) * 67 + h * 16;
        const float* r1 = r0 + 67;
        const float* xh = x + h * 16;
        float s0 = 0.0f, s1 = 0.0f;
#pragma unroll
        for (int c = 0; c < 16; ++c) {
            const float xc = xh[c];
            s0 = fmaf(r0[c], xc, s0);
            s1 = fmaf(r1[c], xc, s1);
        }
        float2* psum = (float2*)&s_u[10240];   // [h][p], 4 x 64 float2
        psum[h * 64 + p] = make_float2(s0, s1);
    }
    // W2 [64][128] -> f16 A-frag staging (pairs along k)
    const float2* W2v = (const float2*)W2;
#pragma unroll
    for (int it = 0; it < 16; ++it) {
        int pidx = t + 256 * it;
        int idx2 = pidx * 2;
        int o = idx2 >> 7, k = idx2 & 127;
        int mt = o >> 4, lm = o & 15;
        int kb = k >> 5, q = (k >> 3) & 3, jj = k & 7;
        float2 v = W2v[pidx];
        *(unsigned*)&s_u[(mt * 4 + kb) * 512 + (q * 16 + lm) * 8 + jj] =
            h2u(__builtin_amdgcn_cvt_pkrtz(v.x, v.y));
    }
    // W3 [32][64] -> f16 A-frag staging
    const float2* W3v = (const float2*)W3;
#pragma unroll
    for (int it = 0; it < 4; ++it) {
        int pidx = t + 256 * it;
        int idx2 = pidx * 2;
        int o = idx2 >> 6, k = idx2 & 63;
        int mt = o >> 4, lm = o & 15;
        int kb = k >> 5, q = (k >> 3) & 3, jj = k & 7;
        float2 v = W3v[pidx];
        *(unsigned*)&s_u[8192 + (mt * 2 + kb) * 512 + (q * 16 + lm) * 8 + jj] =
            h2u(__builtin_amdgcn_cvt_pkrtz(v.x, v.y));
    }
    if (t < 64) s_b2[t] = b2[t];
    if (t < 32) {
        s_b3[t] = b3[t];
        s_w4[t] = W4[t];
    }
    const float bias4 = b4[0];
    __syncthreads();

    // ================= prep phase 2 (t<64): combine partials + pack tables ====
    if (t < 64) {
        const float2* psum = (const float2*)&s_u[10240];
        float2 q0 = psum[t], q1 = psum[64 + t], q2 = psum[128 + t], q3 = psum[192 + t];
        float s0 = b1[2 * t] + (q0.x + q1.x) + (q2.x + q3.x);
        float s1 = b1[2 * t + 1] + (q0.y + q1.y) + (q2.y + q3.y);
        const float* r0 = W1 + (2 * t) * 67;
        const float* r1 = r0 + 67;
        const float pa = -1.0f + step * (float)(blockIdx.x >> 3);   // gi
        const float base0 = fmaf(r0[64], pa, s0);
        const float base1 = fmaf(r1[64], pa, s1);
        const float wb0 = r0[65], wb1 = r1[65];
        const int gj0 = (blockIdx.x & 7) * 16;
        s_wcp[t] = h2u(__builtin_amdgcn_cvt_pkrtz(r0[66], r1[66]));
#pragma unroll
        for (int j = 0; j < 16; ++j) {
            const float pb = -1.0f + step * (float)(gj0 + j);
            s_basep[j][t] = h2u(__builtin_amdgcn_cvt_pkrtz(
                fmaf(wb0, pb, base0), fmaf(wb1, pb, base1)));
        }
    }
    __syncthreads();

    // ================= per-wave fragment preload =================
    // Only the MFMA A-operands stay register-resident (a2=64 + a3=16 AGPR).
    // b2/b3/w4 constants are NOT preloaded (R25): they are re-read from LDS
    // inside the loop via volatile broadcast reads to fit 3 waves/SIMD.
    h16x8_t a2[16];
#pragma unroll
    for (int f = 0; f < 16; ++f) a2[f] = *(const h16x8_t*)&s_u[f * 512 + lane * 8];
    h16x8_t a3[4];
#pragma unroll
    for (int f = 0; f < 4; ++f) a3[f] = *(const h16x8_t*)&s_u[8192 + f * 512 + lane * 8];
    // wc pairs: loop-invariant, 16 packed regs, pinned
    unsigned twp[16];
#pragma unroll
    for (int kb = 0; kb < 4; ++kb) {
        uint4 v = *(const uint4*)&s_wcp[kb * 16 + quad * 4];
        twp[kb * 4 + 0] = v.x; twp[kb * 4 + 1] = v.y;
        twp[kb * 4 + 2] = v.z; twp[kb * 4 + 3] = v.w;
    }
#pragma unroll
    for (int i = 0; i < 16; ++i) asm volatile("" : "+v"(twp[i]));
    __syncthreads();  // union handoff: staging -> h2/zf scratch

    const int sw = (l15 & 1) * 32;                    // h2 channel swizzle (shorts)
    unsigned short* h2w = &s_u[w * 2 * 1152];         // 2 slots x 16 pts x 72 shorts
    float* zf = (float*)&s_u[9216];                   // [w][pg&7][i][q]
    const f32x2_t zero2 = {0.0f, 0.0f};
    const g16x2_t zero2h = {(__fp16)0.0f, (__fp16)0.0f};
    const int outbase = blockIdx.x * 2048 + w * 512;

    // B-phase tail: layer 3 + w4-dot using PRELOADED h2 fragments.
    // b3 bias (C-init) and w4 weights are volatile LDS reads (per call):
    // broadcast within quad, conflict-free, issued early -> latency hidden
    // by the extra resident wave.
    auto bphase = [&](int pg, h16x8_t b3f0, h16x8_t b3f1) {
        f32x2_t z2 = zero2;
#pragma unroll
        for (int mt = 0; mt < 2; ++mt) {
            f32x4_t c = ldsv4(&s_b3[mt * 16 + quad * 4]);
            f32x4_t wq = ldsv4(&s_w4[mt * 16 + quad * 4]);
            c = __builtin_amdgcn_mfma_f32_16x16x32_f16(a3[mt * 2 + 0], b3f0, c, 0, 0, 0);
            c = __builtin_amdgcn_mfma_f32_16x16x32_f16(a3[mt * 2 + 1], b3f1, c, 0, 0, 0);
            f32x2_t h01 = __builtin_elementwise_max((f32x2_t){c[0], c[1]}, zero2);
            f32x2_t h23 = __builtin_elementwise_max((f32x2_t){c[2], c[3]}, zero2);
            z2 = __builtin_elementwise_fma((f32x2_t){wq[0], wq[1]}, h01, z2);
            z2 = __builtin_elementwise_fma((f32x2_t){wq[2], wq[3]}, h23, z2);
        }
        zf[w * 512 + (pg & 7) * 64 + l15 * 4 + quad] = z2[0] + z2[1];
    };
    // phase C: batched reduce + sigmoid + coalesced store for an 8-ng batch
    auto cphase = [&](int batch) {
#pragma unroll
        for (int half = 0; half < 2; ++half) {
            const int p = lane + 64 * half;   // point within this batch's 128
            const int pg = p >> 4, i = p & 15;
            float4 v = *(const float4*)&zf[w * 512 + pg * 64 + i * 4];
            float z = (v.x + v.y) + (v.z + v.w) + bias4;
            out[outbase + batch * 128 + p] = 1.0f / (1.0f + __expf(-z));
        }
    };

    // ========== jrow-outer main loop ==========
    for (int jrow = 0; jrow < 4; ++jrow) {
        // base pairs for this jrow: 16 packed regs, pinned
        const unsigned* bp = &s_basep[w * 4 + jrow][0];
        unsigned tbp[16];
#pragma unroll
        for (int kb = 0; kb < 4; ++kb) {
            uint4 v = *(const uint4*)&bp[kb * 16 + quad * 4];
            tbp[kb * 4 + 0] = v.x; tbp[kb * 4 + 1] = v.y;
            tbp[kb * 4 + 2] = v.z; tbp[kb * 4 + 3] = v.w;
        }
#pragma unroll
        for (int i = 0; i < 16; ++i) asm volatile("" : "+v"(tbp[i]));

#pragma unroll 2
        for (int pg = 0; pg < 8; ++pg) {
            const int ng = jrow * 8 + pg;
            // ---- per-group C-init bias: volatile broadcast LDS reads ----
            f32x4_t c2i[4];
#pragma unroll
            for (int mt = 0; mt < 4; ++mt) c2i[mt] = ldsv4(&s_b2[mt * 16 + quad * 4]);
            // ---- prefetch h2 fragments for bphase(ng-1) ----
            h16x8_t b3f0, b3f1;
            if (ng > 0) {
                const unsigned short* pslot = h2w + ((ng - 1) & 1) * 1152 + l15 * 72;
                b3f0 = *(const h16x8_t*)&pslot[(0 ^ sw) + quad * 8];
                b3f1 = *(const h16x8_t*)&pslot[(32 ^ sw) + quad * 8];
            }

            const float pc = fmaf(step, (float)((pg * 16) + l15), -1.0f);
            const g16x2_t pc2 = __builtin_amdgcn_cvt_pkrtz(pc, pc);

            // ---- A1: h1 via packed f16 fma/max, straight into B-fragments ----
            h16x8_t bfrag[4];
#pragma unroll
            for (int kb = 0; kb < 4; ++kb) {
                union { h16x8_t v; g16x2_t h[4]; } bb;
#pragma unroll
                for (int p = 0; p < 4; ++p) {
                    g16x2_t hh = __builtin_elementwise_fma(
                        u2h(twp[kb * 4 + p]), pc2, u2h(tbp[kb * 4 + p]));
                    bb.h[p] = __builtin_elementwise_max(hh, zero2h);
                }
                bfrag[kb] = bb.v;
            }
            // ---- A2: layer 2 MFMA (f16), bias in C-init ----
            f32x4_t acc2[4];
#pragma unroll
            for (int mt = 0; mt < 4; ++mt) {
                f32x4_t c = c2i[mt];
#pragma unroll
                for (int kb = 0; kb < 4; ++kb)
                    c = __builtin_amdgcn_mfma_f32_16x16x32_f16(a2[mt * 4 + kb], bfrag[kb], c, 0, 0, 0);
                acc2[mt] = c;
            }
            // ---- A3: pack (cvt_pkrtz) + relu (pk_max_f16) + write h2 slot ----
            unsigned short* slot = h2w + (ng & 1) * 1152 + l15 * 72;
#pragma unroll
            for (int mt = 0; mt < 4; ++mt) {
                g16x2_t lo = __builtin_elementwise_max(
                    __builtin_amdgcn_cvt_pkrtz(acc2[mt][0], acc2[mt][1]), zero2h);
                g16x2_t hi = __builtin_elementwise_max(
                    __builtin_amdgcn_cvt_pkrtz(acc2[mt][2], acc2[mt][3]), zero2h);
                uint2 pk;
                pk.x = h2u(lo);
                pk.y = h2u(hi);
                *(uint2*)&slot[(mt * 16 + quad * 4) ^ sw] = pk;
            }
            // ---- B for previous group (fragments already in registers) ----
            if (ng > 0) {
                bphase(ng - 1, b3f0, b3f1);
                if (((ng - 1) & 7) == 7) cphase((ng - 1) >> 3);
            }
        }
    }
    {   // drain: bphase(31) with direct reads
        const unsigned short* pslot = h2w + (31 & 1) * 1152 + l15 * 72;
        h16x8_t b3f0 = *(const h16x8_t*)&pslot[(0 ^ sw) + quad * 8];
        h16x8_t b3f1 = *(const h16x8_t*)&pslot[(32 ^ sw) + quad * 8];
        bphase(31, b3f0, b3f1);
        cphase(3);
    }
}

extern "C" void kernel_launch(void* const* d_in, const int* in_sizes, int n_in,
                              void* d_out, int out_size, void* d_ws, size_t ws_size,
                              hipStream_t stream) {
    mlp_kernel<<<NPTS / 2048, 256, 0, stream>>>(
        (const float*)d_in[0], (const float*)d_in[1], (const float*)d_in[2],
        (const float*)d_in[3], (const float*)d_in[4], (const float*)d_in[5],
        (const float*)d_in[6], (const float*)d_in[7], (const float*)d_in[8],
        (float*)d_out);
}

// Round 4
// 114.308 us; speedup vs baseline: 1.5267x; 1.5267x over previous
//
#include <hip/hip_runtime.h>
#include <hip/hip_bf16.h>
#include <hip/hip_fp16.h>

// GeneratorSDF: latent-conditioned MLP SDF on a 128^3 grid (fp32 I/O).
// dims: 67 -> 128 -> 64 -> 32 -> 1 (relu, relu, relu, sigmoid)
//
// R26 = R22 (best verified: 53.5us) + T5 s_setprio around MFMA clusters.
// Ledger: R23 (LDS->permlane) +VALU -> -6%; R24 (+reg pipeline) -> -9%;
// R25 ((256,3) via reg demotion) -> scratch spills (FETCH 346K->8.4M,
// WRITE 8.2M->28M), -150%. Conclusions now triple-confirmed:
//   (1) 2 waves/SIMD is a register-file hard floor (a2=64 AGPR irreducible);
//   (2) every VALU instr added to the chain costs ~1:1 (nothing hides it);
//   (3) at 815 TF-equiv / MfmaUtil 32 we sit at the m97-class structural
//       ceiling (~33-37% of peak) for simply-scheduled MFMA kernels.
// Remaining zero-instruction lever: cross-wave issue arbitration. The 4
// waves/block run barrier-free at independent phases (attn-like regime,
// m191: +4-7%; NOT lockstep-GEMM m190 null). setprio(1) during the A2
// 16-MFMA burst and bphase 4-MFMA burst lets the MFMA-entering wave win
// issue slots over co-resident A1/A3-VALU waves, filling phase-boundary
// bubbles. Everything else is byte-identical R22: fp16 datapath, h2 LDS
// double-buffer + b3f prefetch, batched cphase, pinned twp/tbp, jrow-outer
// 4x8, 4-way-parallel W1 fold, (256,2), grid 1024 (2048 pts/block).
// MFMA layouts (verified m89/m91): A[m=lane&15][k=quad*8+j],
// B[k=quad*8+j][n=lane&15], C/D row=quad*4+reg, col=lane&15.

#define NPTS (128 * 128 * 128)

typedef float f32x4_t __attribute__((ext_vector_type(4)));
typedef float f32x2_t __attribute__((ext_vector_type(2)));
typedef __fp16 g16x2_t __attribute__((ext_vector_type(2)));    // VALU half2 (cvt_pkrtz type)
typedef _Float16 h16x8_t __attribute__((ext_vector_type(8)));  // MFMA fragment

__device__ __forceinline__ unsigned h2u(g16x2_t h) {
    unsigned u;
    __builtin_memcpy(&u, &h, 4);
    return u;
}
__device__ __forceinline__ g16x2_t u2h(unsigned u) {
    g16x2_t h;
    __builtin_memcpy(&h, &u, 4);
    return h;
}

__global__ __launch_bounds__(256, 2) void mlp_kernel(
    const float* __restrict__ x,  const float* __restrict__ W1,
    const float* __restrict__ b1, const float* __restrict__ W2,
    const float* __restrict__ b2, const float* __restrict__ W3,
    const float* __restrict__ b3, const float* __restrict__ W4,
    const float* __restrict__ b4, float* __restrict__ out) {
    __shared__ __align__(16) unsigned s_basep[16][64];  // half2 {base[2c],base[2c+1]} per j
    __shared__ __align__(16) unsigned s_wcp[64];        // half2 wc pairs
    __shared__ __align__(16) float s_b2[64];
    __shared__ __align__(16) float s_b3[32];
    __shared__ __align__(16) float s_w4[32];
    // Union (26.6 KB): staging = w2a[16][64][8] halves (0..8191) + w3a[4][64][8]
    // (8192..10239) + W1-fold partials (floats at shorts 10240..11263, transient);
    // runtime = h2 slots [w][2][16][72] (0..9215) + zf floats
    // (shorts 9216..13311 = float[4][8][16][4] : w*512 + pg*64 + i*4 + q).
    __shared__ __align__(16) unsigned short s_u[13312];

    const int t = threadIdx.x;
    const int w = t >> 6;
    const int lane = t & 63;
    const int quad = lane >> 4;
    const int l15 = lane & 15;
    const float step = 2.0f / 127.0f;

    // ================= per-block prep, phase 1 (all 256 threads) =============
    // W1 fold partials: thread covers channel-pair p = t&63, c in [h*16,(h+1)*16)
    {
        const int p = t & 63, h = t >> 6;
        const float* r0 = W1 + (2 * p) * 67 + h * 16;
        const float* r1 = r0 + 67;
        const float* xh = x + h * 16;
        float s0 = 0.0f, s1 = 0.0f;
#pragma unroll
        for (int c = 0; c < 16; ++c) {
            const float xc = xh[c];
            s0 = fmaf(r0[c], xc, s0);
            s1 = fmaf(r1[c], xc, s1);
        }
        float2* psum = (float2*)&s_u[10240];   // [h][p], 4 x 64 float2
        psum[h * 64 + p] = make_float2(s0, s1);
    }
    // W2 [64][128] -> f16 A-frag staging (pairs along k)
    const float2* W2v = (const float2*)W2;
#pragma unroll
    for (int it = 0; it < 16; ++it) {
        int pidx = t + 256 * it;
        int idx2 = pidx * 2;
        int o = idx2 >> 7, k = idx2 & 127;
        int mt = o >> 4, lm = o & 15;
        int kb = k >> 5, q = (k >> 3) & 3, jj = k & 7;
        float2 v = W2v[pidx];
        *(unsigned*)&s_u[(mt * 4 + kb) * 512 + (q * 16 + lm) * 8 + jj] =
            h2u(__builtin_amdgcn_cvt_pkrtz(v.x, v.y));
    }
    // W3 [32][64] -> f16 A-frag staging
    const float2* W3v = (const float2*)W3;
#pragma unroll
    for (int it = 0; it < 4; ++it) {
        int pidx = t + 256 * it;
        int idx2 = pidx * 2;
        int o = idx2 >> 6, k = idx2 & 63;
        int mt = o >> 4, lm = o & 15;
        int kb = k >> 5, q = (k >> 3) & 3, jj = k & 7;
        float2 v = W3v[pidx];
        *(unsigned*)&s_u[8192 + (mt * 2 + kb) * 512 + (q * 16 + lm) * 8 + jj] =
            h2u(__builtin_amdgcn_cvt_pkrtz(v.x, v.y));
    }
    if (t < 64) s_b2[t] = b2[t];
    if (t < 32) {
        s_b3[t] = b3[t];
        s_w4[t] = W4[t];
    }
    const float bias4 = b4[0];
    __syncthreads();

    // ================= prep phase 2 (t<64): combine partials + pack tables ====
    if (t < 64) {
        const float2* psum = (const float2*)&s_u[10240];
        float2 q0 = psum[t], q1 = psum[64 + t], q2 = psum[128 + t], q3 = psum[192 + t];
        float s0 = b1[2 * t] + (q0.x + q1.x) + (q2.x + q3.x);
        float s1 = b1[2 * t + 1] + (q0.y + q1.y) + (q2.y + q3.y);
        const float* r0 = W1 + (2 * t) * 67;
        const float* r1 = r0 + 67;
        const float pa = -1.0f + step * (float)(blockIdx.x >> 3);   // gi
        const float base0 = fmaf(r0[64], pa, s0);
        const float base1 = fmaf(r1[64], pa, s1);
        const float wb0 = r0[65], wb1 = r1[65];
        const int gj0 = (blockIdx.x & 7) * 16;
        s_wcp[t] = h2u(__builtin_amdgcn_cvt_pkrtz(r0[66], r1[66]));
#pragma unroll
        for (int j = 0; j < 16; ++j) {
            const float pb = -1.0f + step * (float)(gj0 + j);
            s_basep[j][t] = h2u(__builtin_amdgcn_cvt_pkrtz(
                fmaf(wb0, pb, base0), fmaf(wb1, pb, base1)));
        }
    }
    __syncthreads();

    // ================= per-wave fragment preload =================
    h16x8_t a2[16];
#pragma unroll
    for (int f = 0; f < 16; ++f) a2[f] = *(const h16x8_t*)&s_u[f * 512 + lane * 8];
    h16x8_t a3[4];
#pragma unroll
    for (int f = 0; f < 4; ++f) a3[f] = *(const h16x8_t*)&s_u[8192 + f * 512 + lane * 8];
    f32x4_t b2q[4];
#pragma unroll
    for (int mt = 0; mt < 4; ++mt) b2q[mt] = *(const f32x4_t*)&s_b2[mt * 16 + quad * 4];
    f32x4_t b3q[2];
    f32x2_t w4lo[2], w4hi[2];
#pragma unroll
    for (int mt = 0; mt < 2; ++mt) {
        b3q[mt] = *(const f32x4_t*)&s_b3[mt * 16 + quad * 4];
        float4 wq = *(const float4*)&s_w4[mt * 16 + quad * 4];
        w4lo[mt][0] = wq.x; w4lo[mt][1] = wq.y;
        w4hi[mt][0] = wq.z; w4hi[mt][1] = wq.w;
    }
    // wc pairs: loop-invariant, 16 packed regs, pinned
    unsigned twp[16];
#pragma unroll
    for (int kb = 0; kb < 4; ++kb) {
        uint4 v = *(const uint4*)&s_wcp[kb * 16 + quad * 4];
        twp[kb * 4 + 0] = v.x; twp[kb * 4 + 1] = v.y;
        twp[kb * 4 + 2] = v.z; twp[kb * 4 + 3] = v.w;
    }
#pragma unroll
    for (int i = 0; i < 16; ++i) asm volatile("" : "+v"(twp[i]));
    __syncthreads();  // union handoff: staging -> h2/zf scratch

    const int sw = (l15 & 1) * 32;                    // h2 channel swizzle (shorts)
    unsigned short* h2w = &s_u[w * 2 * 1152];         // 2 slots x 16 pts x 72 shorts
    float* zf = (float*)&s_u[9216];                   // [w][pg&7][i][q]
    const f32x2_t zero2 = {0.0f, 0.0f};
    const g16x2_t zero2h = {(__fp16)0.0f, (__fp16)0.0f};
    const int outbase = blockIdx.x * 2048 + w * 512;

    // B-phase tail: layer 3 + w4-dot using PRELOADED h2 fragments.
    // T5: raise wave priority for the MFMA burst (waves are phase-independent).
    auto bphase = [&](int pg, h16x8_t b3f0, h16x8_t b3f1) {
        f32x2_t z2 = zero2;
        __builtin_amdgcn_s_setprio(1);
#pragma unroll
        for (int mt = 0; mt < 2; ++mt) {
            f32x4_t c = b3q[mt];
            c = __builtin_amdgcn_mfma_f32_16x16x32_f16(a3[mt * 2 + 0], b3f0, c, 0, 0, 0);
            c = __builtin_amdgcn_mfma_f32_16x16x32_f16(a3[mt * 2 + 1], b3f1, c, 0, 0, 0);
            f32x2_t h01 = __builtin_elementwise_max((f32x2_t){c[0], c[1]}, zero2);
            f32x2_t h23 = __builtin_elementwise_max((f32x2_t){c[2], c[3]}, zero2);
            z2 = __builtin_elementwise_fma(w4lo[mt], h01, z2);
            z2 = __builtin_elementwise_fma(w4hi[mt], h23, z2);
        }
        __builtin_amdgcn_s_setprio(0);
        zf[w * 512 + (pg & 7) * 64 + l15 * 4 + quad] = z2[0] + z2[1];
    };
    // phase C: batched reduce + sigmoid + coalesced store for an 8-ng batch
    auto cphase = [&](int batch) {
#pragma unroll
        for (int half = 0; half < 2; ++half) {
            const int p = lane + 64 * half;   // point within this batch's 128
            const int pg = p >> 4, i = p & 15;
            float4 v = *(const float4*)&zf[w * 512 + pg * 64 + i * 4];
            float z = (v.x + v.y) + (v.z + v.w) + bias4;
            out[outbase + batch * 128 + p] = 1.0f / (1.0f + __expf(-z));
        }
    };

    // ========== jrow-outer main loop ==========
    for (int jrow = 0; jrow < 4; ++jrow) {
        // base pairs for this jrow: 16 packed regs, pinned
        const unsigned* bp = &s_basep[w * 4 + jrow][0];
        unsigned tbp[16];
#pragma unroll
        for (int kb = 0; kb < 4; ++kb) {
            uint4 v = *(const uint4*)&bp[kb * 16 + quad * 4];
            tbp[kb * 4 + 0] = v.x; tbp[kb * 4 + 1] = v.y;
            tbp[kb * 4 + 2] = v.z; tbp[kb * 4 + 3] = v.w;
        }
#pragma unroll
        for (int i = 0; i < 16; ++i) asm volatile("" : "+v"(tbp[i]));

#pragma unroll 2
        for (int pg = 0; pg < 8; ++pg) {
            const int ng = jrow * 8 + pg;
            // ---- prefetch h2 fragments for bphase(ng-1) ----
            h16x8_t b3f0, b3f1;
            if (ng > 0) {
                const unsigned short* pslot = h2w + ((ng - 1) & 1) * 1152 + l15 * 72;
                b3f0 = *(const h16x8_t*)&pslot[(0 ^ sw) + quad * 8];
                b3f1 = *(const h16x8_t*)&pslot[(32 ^ sw) + quad * 8];
            }

            const float pc = fmaf(step, (float)((pg * 16) + l15), -1.0f);
            const g16x2_t pc2 = __builtin_amdgcn_cvt_pkrtz(pc, pc);

            // ---- A1: h1 via packed f16 fma/max, straight into B-fragments ----
            h16x8_t bfrag[4];
#pragma unroll
            for (int kb = 0; kb < 4; ++kb) {
                union { h16x8_t v; g16x2_t h[4]; } bb;
#pragma unroll
                for (int p = 0; p < 4; ++p) {
                    g16x2_t hh = __builtin_elementwise_fma(
                        u2h(twp[kb * 4 + p]), pc2, u2h(tbp[kb * 4 + p]));
                    bb.h[p] = __builtin_elementwise_max(hh, zero2h);
                }
                bfrag[kb] = bb.v;
            }
            // ---- A2: layer 2 MFMA (f16), bias in C-init; T5 priority burst ----
            f32x4_t acc2[4];
            __builtin_amdgcn_s_setprio(1);
#pragma unroll
            for (int mt = 0; mt < 4; ++mt) {
                f32x4_t c = b2q[mt];
#pragma unroll
                for (int kb = 0; kb < 4; ++kb)
                    c = __builtin_amdgcn_mfma_f32_16x16x32_f16(a2[mt * 4 + kb], bfrag[kb], c, 0, 0, 0);
                acc2[mt] = c;
            }
            __builtin_amdgcn_s_setprio(0);
            // ---- A3: pack (cvt_pkrtz) + relu (pk_max_f16) + write h2 slot ----
            unsigned short* slot = h2w + (ng & 1) * 1152 + l15 * 72;
#pragma unroll
            for (int mt = 0; mt < 4; ++mt) {
                g16x2_t lo = __builtin_elementwise_max(
                    __builtin_amdgcn_cvt_pkrtz(acc2[mt][0], acc2[mt][1]), zero2h);
                g16x2_t hi = __builtin_elementwise_max(
                    __builtin_amdgcn_cvt_pkrtz(acc2[mt][2], acc2[mt][3]), zero2h);
                uint2 pk;
                pk.x = h2u(lo);
                pk.y = h2u(hi);
                *(uint2*)&slot[(mt * 16 + quad * 4) ^ sw] = pk;
            }
            // ---- B for previous group (fragments already in registers) ----
            if (ng > 0) {
                bphase(ng - 1, b3f0, b3f1);
                if (((ng - 1) & 7) == 7) cphase((ng - 1) >> 3);
            }
        }
    }
    {   // drain: bphase(31) with direct reads
        const unsigned short* pslot = h2w + (31 & 1) * 1152 + l15 * 72;
        h16x8_t b3f0 = *(const h16x8_t*)&pslot[(0 ^ sw) + quad * 8];
        h16x8_t b3f1 = *(const h16x8_t*)&pslot[(32 ^ sw) + quad * 8];
        bphase(31, b3f0, b3f1);
        cphase(3);
    }
}

extern "C" void kernel_launch(void* const* d_in, const int* in_sizes, int n_in,
                              void* d_out, int out_size, void* d_ws, size_t ws_size,
                              hipStream_t stream) {
    mlp_kernel<<<NPTS / 2048, 256, 0, stream>>>(
        (const float*)d_in[0], (const float*)d_in[1], (const float*)d_in[2],
        (const float*)d_in[3], (const float*)d_in[4], (const float*)d_in[5],
        (const float*)d_in[6], (const float*)d_in[7], (const float*)d_in[8],
        (float*)d_out);
}

// Round 5
// 112.876 us; speedup vs baseline: 1.5461x; 1.0127x over previous
//
#include <hip/hip_runtime.h>
#include <hip/hip_bf16.h>
#include <hip/hip_fp16.h>

// GeneratorSDF: latent-conditioned MLP SDF on a 128^3 grid (fp32 I/O).
// dims: 67 -> 128 -> 64 -> 32 -> 1 (relu, relu, relu, sigmoid)
//
// R27 = R22 core + dual-rail ILP=2 + grid 512 (4096 pts/block).
// Ledger: R22 53.5us (best). R23 LDS->permlane: -6% (added VALU costs 1:1).
// R24 reg-pipeline: -9%. R25 (256,3): spill catastrophe (FETCH 346K->8.4M).
// R26 setprio: null. Model: VALUBusy 42 + MfmaUtil 32 -> ~26% of cycles NO
// pipe issues = per-wave dependency latency; TLP capped at 2 waves/SIMD by
// the register file (R25), but at 2 waves the per-wave budget is 256 regs
// and we use only ~180 (100 VGPR + 80 AGPR) -> spend the ~76 free regs on
// ILP: two independent 16-pt rails per iteration (own bfrag/acc2/b3f;
// shared a2/a3/twp/tbp/b2q/b3q/w4). Grid 512: one residency round instead
// of two, prep amortized 2x. Per-point VALU/MFMA/LDS counts UNCHANGED.
// h2 now 4 slots/wave (write ng&3, read (ng-2)&3); s_basep[32][64];
// LDS ~54KB -> still 2 blocks/CU. Pre-committed failure reads: FETCH>>350KB
// = spill; Occupancy<12% = 1 wave/SIMD; either -> revert to R22 core.
// MFMA layouts (verified m89/m91): A[m=lane&15][k=quad*8+j],
// B[k=quad*8+j][n=lane&15], C/D row=quad*4+reg, col=lane&15.

#define NPTS (128 * 128 * 128)

typedef float f32x4_t __attribute__((ext_vector_type(4)));
typedef float f32x2_t __attribute__((ext_vector_type(2)));
typedef __fp16 g16x2_t __attribute__((ext_vector_type(2)));    // VALU half2 (cvt_pkrtz type)
typedef _Float16 h16x8_t __attribute__((ext_vector_type(8)));  // MFMA fragment

__device__ __forceinline__ unsigned h2u(g16x2_t h) {
    unsigned u;
    __builtin_memcpy(&u, &h, 4);
    return u;
}
__device__ __forceinline__ g16x2_t u2h(unsigned u) {
    g16x2_t h;
    __builtin_memcpy(&h, &u, 4);
    return h;
}

__global__ __launch_bounds__(256, 2) void mlp_kernel(
    const float* __restrict__ x,  const float* __restrict__ W1,
    const float* __restrict__ b1, const float* __restrict__ W2,
    const float* __restrict__ b2, const float* __restrict__ W3,
    const float* __restrict__ b3, const float* __restrict__ W4,
    const float* __restrict__ b4, float* __restrict__ out) {
    __shared__ __align__(16) unsigned s_basep[32][64];  // half2 {base[2c],base[2c+1]} per j
    __shared__ __align__(16) unsigned s_wcp[64];        // half2 wc pairs
    __shared__ __align__(16) float s_b2[64];
    __shared__ __align__(16) float s_b3[32];
    __shared__ __align__(16) float s_w4[32];
    // Union (45 KB): staging = w2a[16][64][8] halves (0..8191) + w3a[4][64][8]
    // (8192..10239) + W1-fold partials (floats at shorts 10240..11263, transient);
    // runtime = h2 slots [w][4][16][72] shorts (0..18431) + zf floats
    // (shorts 18432..22527 = float[4][8][16][4] : w*512 + pg7*64 + i*4 + q).
    __shared__ __align__(16) unsigned short s_u[22528];

    const int t = threadIdx.x;
    const int w = t >> 6;
    const int lane = t & 63;
    const int quad = lane >> 4;
    const int l15 = lane & 15;
    const float step = 2.0f / 127.0f;

    // ================= per-block prep, phase 1 (all 256 threads) =============
    // W1 fold partials: thread covers channel-pair p = t&63, c in [h*16,(h+1)*16)
    {
        const int p = t & 63, h = t >> 6;
        const float* r0 = W1 + (2 * p) * 67 + h * 16;
        const float* r1 = r0 + 67;
        const float* xh = x + h * 16;
        float s0 = 0.0f, s1 = 0.0f;
#pragma unroll
        for (int c = 0; c < 16; ++c) {
            const float xc = xh[c];
            s0 = fmaf(r0[c], xc, s0);
            s1 = fmaf(r1[c], xc, s1);
        }
        float2* psum = (float2*)&s_u[10240];   // [h][p], 4 x 64 float2
        psum[h * 64 + p] = make_float2(s0, s1);
    }
    // W2 [64][128] -> f16 A-frag staging (pairs along k)
    const float2* W2v = (const float2*)W2;
#pragma unroll
    for (int it = 0; it < 16; ++it) {
        int pidx = t + 256 * it;
        int idx2 = pidx * 2;
        int o = idx2 >> 7, k = idx2 & 127;
        int mt = o >> 4, lm = o & 15;
        int kb = k >> 5, q = (k >> 3) & 3, jj = k & 7;
        float2 v = W2v[pidx];
        *(unsigned*)&s_u[(mt * 4 + kb) * 512 + (q * 16 + lm) * 8 + jj] =
            h2u(__builtin_amdgcn_cvt_pkrtz(v.x, v.y));
    }
    // W3 [32][64] -> f16 A-frag staging
    const float2* W3v = (const float2*)W3;
#pragma unroll
    for (int it = 0; it < 4; ++it) {
        int pidx = t + 256 * it;
        int idx2 = pidx * 2;
        int o = idx2 >> 6, k = idx2 & 63;
        int mt = o >> 4, lm = o & 15;
        int kb = k >> 5, q = (k >> 3) & 3, jj = k & 7;
        float2 v = W3v[pidx];
        *(unsigned*)&s_u[8192 + (mt * 2 + kb) * 512 + (q * 16 + lm) * 8 + jj] =
            h2u(__builtin_amdgcn_cvt_pkrtz(v.x, v.y));
    }
    if (t < 64) s_b2[t] = b2[t];
    if (t < 32) {
        s_b3[t] = b3[t];
        s_w4[t] = W4[t];
    }
    const float bias4 = b4[0];
    __syncthreads();

    // ================= prep phase 2 (t<64): combine partials + pack tables ====
    // Block covers gi = bid>>2 (a-coord), gj0 = (bid&3)*32 (32 j-rows), all k.
    if (t < 64) {
        const float2* psum = (const float2*)&s_u[10240];
        float2 q0 = psum[t], q1 = psum[64 + t], q2 = psum[128 + t], q3 = psum[192 + t];
        float s0 = b1[2 * t] + (q0.x + q1.x) + (q2.x + q3.x);
        float s1 = b1[2 * t + 1] + (q0.y + q1.y) + (q2.y + q3.y);
        const float* r0 = W1 + (2 * t) * 67;
        const float* r1 = r0 + 67;
        const float pa = -1.0f + step * (float)(blockIdx.x >> 2);   // gi
        const float base0 = fmaf(r0[64], pa, s0);
        const float base1 = fmaf(r1[64], pa, s1);
        const float wb0 = r0[65], wb1 = r1[65];
        const int gj0 = (blockIdx.x & 3) * 32;
        s_wcp[t] = h2u(__builtin_amdgcn_cvt_pkrtz(r0[66], r1[66]));
#pragma unroll
        for (int j = 0; j < 32; ++j) {
            const float pb = -1.0f + step * (float)(gj0 + j);
            s_basep[j][t] = h2u(__builtin_amdgcn_cvt_pkrtz(
                fmaf(wb0, pb, base0), fmaf(wb1, pb, base1)));
        }
    }
    __syncthreads();

    // ================= per-wave fragment preload =================
    h16x8_t a2[16];
#pragma unroll
    for (int f = 0; f < 16; ++f) a2[f] = *(const h16x8_t*)&s_u[f * 512 + lane * 8];
    h16x8_t a3[4];
#pragma unroll
    for (int f = 0; f < 4; ++f) a3[f] = *(const h16x8_t*)&s_u[8192 + f * 512 + lane * 8];
    f32x4_t b2q[4];
#pragma unroll
    for (int mt = 0; mt < 4; ++mt) b2q[mt] = *(const f32x4_t*)&s_b2[mt * 16 + quad * 4];
    f32x4_t b3q[2];
    f32x2_t w4lo[2], w4hi[2];
#pragma unroll
    for (int mt = 0; mt < 2; ++mt) {
        b3q[mt] = *(const f32x4_t*)&s_b3[mt * 16 + quad * 4];
        float4 wq = *(const float4*)&s_w4[mt * 16 + quad * 4];
        w4lo[mt][0] = wq.x; w4lo[mt][1] = wq.y;
        w4hi[mt][0] = wq.z; w4hi[mt][1] = wq.w;
    }
    // wc pairs: loop-invariant, 16 packed regs, pinned
    unsigned twp[16];
#pragma unroll
    for (int kb = 0; kb < 4; ++kb) {
        uint4 v = *(const uint4*)&s_wcp[kb * 16 + quad * 4];
        twp[kb * 4 + 0] = v.x; twp[kb * 4 + 1] = v.y;
        twp[kb * 4 + 2] = v.z; twp[kb * 4 + 3] = v.w;
    }
#pragma unroll
    for (int i = 0; i < 16; ++i) asm volatile("" : "+v"(twp[i]));
    __syncthreads();  // union handoff: staging -> h2/zf scratch

    const int sw = (l15 & 1) * 32;                    // h2 channel swizzle (shorts)
    unsigned short* h2w = &s_u[w * 4608];             // 4 slots x 16 pts x 72 shorts
    float* zf = (float*)&s_u[18432];                  // [w][pg&7][i][q]
    const f32x2_t zero2 = {0.0f, 0.0f};
    const g16x2_t zero2h = {(__fp16)0.0f, (__fp16)0.0f};
    const int outbase = blockIdx.x * 4096 + w * 1024;

    // B-phase tail: layer 3 + w4-dot using preloaded h2 fragments
    auto bphase = [&](int pg, h16x8_t b3f0, h16x8_t b3f1) {
        f32x2_t z2 = zero2;
#pragma unroll
        for (int mt = 0; mt < 2; ++mt) {
            f32x4_t c = b3q[mt];
            c = __builtin_amdgcn_mfma_f32_16x16x32_f16(a3[mt * 2 + 0], b3f0, c, 0, 0, 0);
            c = __builtin_amdgcn_mfma_f32_16x16x32_f16(a3[mt * 2 + 1], b3f1, c, 0, 0, 0);
            f32x2_t h01 = __builtin_elementwise_max((f32x2_t){c[0], c[1]}, zero2);
            f32x2_t h23 = __builtin_elementwise_max((f32x2_t){c[2], c[3]}, zero2);
            z2 = __builtin_elementwise_fma(w4lo[mt], h01, z2);
            z2 = __builtin_elementwise_fma(w4hi[mt], h23, z2);
        }
        zf[w * 512 + (pg & 7) * 64 + l15 * 4 + quad] = z2[0] + z2[1];
    };
    // phase C: batched reduce + sigmoid + coalesced store for an 8-ng batch
    auto cphase = [&](int batch) {
#pragma unroll
        for (int half = 0; half < 2; ++half) {
            const int p = lane + 64 * half;   // point within this batch's 128
            const int pg = p >> 4, i = p & 15;
            float4 v = *(const float4*)&zf[w * 512 + pg * 64 + i * 4];
            float z = (v.x + v.y) + (v.z + v.w) + bias4;
            out[outbase + batch * 128 + p] = 1.0f / (1.0f + __expf(-z));
        }
    };
    // A-phase (layer 1 + layer 2) for one 16-pt group at within-jrow pos pgk
    // (uses current jrow's tbp via capture); result in acc[4].
    unsigned tbp[16];
    auto aphase = [&](int pgk, f32x4_t acc[4]) {
        const float pc = fmaf(step, (float)((pgk * 16) + l15), -1.0f);
        const g16x2_t pc2 = __builtin_amdgcn_cvt_pkrtz(pc, pc);
        h16x8_t bfrag[4];
#pragma unroll
        for (int kb = 0; kb < 4; ++kb) {
            union { h16x8_t v; g16x2_t h[4]; } bb;
#pragma unroll
            for (int p = 0; p < 4; ++p) {
                g16x2_t hh = __builtin_elementwise_fma(
                    u2h(twp[kb * 4 + p]), pc2, u2h(tbp[kb * 4 + p]));
                bb.h[p] = __builtin_elementwise_max(hh, zero2h);
            }
            bfrag[kb] = bb.v;
        }
#pragma unroll
        for (int mt = 0; mt < 4; ++mt) {
            f32x4_t c = b2q[mt];
#pragma unroll
            for (int kb = 0; kb < 4; ++kb)
                c = __builtin_amdgcn_mfma_f32_16x16x32_f16(a2[mt * 4 + kb], bfrag[kb], c, 0, 0, 0);
            acc[mt] = c;
        }
    };
    // A3: pack (cvt_pkrtz) + relu (pk_max_f16) + write h2 slot ng&3
    auto a3store = [&](int ng, const f32x4_t acc[4]) {
        unsigned short* slot = h2w + (ng & 3) * 1152 + l15 * 72;
#pragma unroll
        for (int mt = 0; mt < 4; ++mt) {
            g16x2_t lo = __builtin_elementwise_max(
                __builtin_amdgcn_cvt_pkrtz(acc[mt][0], acc[mt][1]), zero2h);
            g16x2_t hi = __builtin_elementwise_max(
                __builtin_amdgcn_cvt_pkrtz(acc[mt][2], acc[mt][3]), zero2h);
            uint2 pk;
            pk.x = h2u(lo);
            pk.y = h2u(hi);
            *(uint2*)&slot[(mt * 16 + quad * 4) ^ sw] = pk;
        }
    };

    // ========== jrow-outer main loop: 8 jrows x 4 pair-iterations ==========
    // Wave w owns jrows [w*8, w*8+8); group ng = jr*8 + pg, pg in [0,8).
    // Pair-iteration handles A(2i),A(2i+1) and B(2i-2),B(2i-1).
    for (int jr = 0; jr < 8; ++jr) {
        // base pairs for this jrow: 16 packed regs, pinned
        const unsigned* bp = &s_basep[w * 8 + jr][0];
#pragma unroll
        for (int kb = 0; kb < 4; ++kb) {
            uint4 v = *(const uint4*)&bp[kb * 16 + quad * 4];
            tbp[kb * 4 + 0] = v.x; tbp[kb * 4 + 1] = v.y;
            tbp[kb * 4 + 2] = v.z; tbp[kb * 4 + 3] = v.w;
        }
#pragma unroll
        for (int i = 0; i < 16; ++i) asm volatile("" : "+v"(tbp[i]));

#pragma unroll 2
        for (int pgp = 0; pgp < 4; ++pgp) {
            const int pgX = 2 * pgp, pgY = pgX + 1;
            const int ngX = jr * 8 + pgX, ngY = ngX + 1;
            // ---- prefetch b3f fragments for bphase(ngX-2), bphase(ngY-2) ----
            h16x8_t bxf0, bxf1, byf0, byf1;
            if (ngX > 1) {
                const unsigned short* ps0 = h2w + ((ngX - 2) & 3) * 1152 + l15 * 72;
                bxf0 = *(const h16x8_t*)&ps0[(0 ^ sw) + quad * 8];
                bxf1 = *(const h16x8_t*)&ps0[(32 ^ sw) + quad * 8];
                const unsigned short* ps1 = h2w + ((ngY - 2) & 3) * 1152 + l15 * 72;
                byf0 = *(const h16x8_t*)&ps1[(0 ^ sw) + quad * 8];
                byf1 = *(const h16x8_t*)&ps1[(32 ^ sw) + quad * 8];
            }
            // ---- dual-rail A-phases: independent chains, scheduler weaves ----
            f32x4_t accX[4], accY[4];
            aphase(pgX, accX);
            aphase(pgY, accY);
            a3store(ngX, accX);
            a3store(ngY, accY);
            // ---- B-phases for the previous pair (slots (ng-2)&3, disjoint) ----
            if (ngX > 1) {
                bphase(ngX - 2, bxf0, bxf1);
                bphase(ngY - 2, byf0, byf1);
                if (((ngY - 2) & 7) == 7) cphase((ngY - 2) >> 3);
            }
        }
    }
    {   // drain: groups 62, 63 + final batch
        const unsigned short* ps0 = h2w + (62 & 3) * 1152 + l15 * 72;
        h16x8_t bxf0 = *(const h16x8_t*)&ps0[(0 ^ sw) + quad * 8];
        h16x8_t bxf1 = *(const h16x8_t*)&ps0[(32 ^ sw) + quad * 8];
        const unsigned short* ps1 = h2w + (63 & 3) * 1152 + l15 * 72;
        h16x8_t byf0 = *(const h16x8_t*)&ps1[(0 ^ sw) + quad * 8];
        h16x8_t byf1 = *(const h16x8_t*)&ps1[(32 ^ sw) + quad * 8];
        bphase(62, bxf0, bxf1);
        bphase(63, byf0, byf1);
        cphase(7);
    }
}

extern "C" void kernel_launch(void* const* d_in, const int* in_sizes, int n_in,
                              void* d_out, int out_size, void* d_ws, size_t ws_size,
                              hipStream_t stream) {
    mlp_kernel<<<NPTS / 4096, 256, 0, stream>>>(
        (const float*)d_in[0], (const float*)d_in[1], (const float*)d_in[2],
        (const float*)d_in[3], (const float*)d_in[4], (const float*)d_in[5],
        (const float*)d_in[6], (const float*)d_in[7], (const float*)d_in[8],
        (float*)d_out);
}

// Round 6
// 111.712 us; speedup vs baseline: 1.5622x; 1.0104x over previous
//
#include <hip/hip_runtime.h>
#include <hip/hip_bf16.h>
#include <hip/hip_fp16.h>

// GeneratorSDF: latent-conditioned MLP SDF on a 128^3 grid (fp32 I/O).
// dims: 67 -> 128 -> 64 -> 32 -> 1 (relu, relu, relu, sigmoid)
//
// R28 = R27 (dual-rail, grid 512, 52.0us) with the rails fused
// INSTRUCTION-BY-INSTRUCTION. R27 post-mortem: +3% only, VGPR 100->116
// (full rail independence needs +40) -> compiler largely serialized the
// rails; sequential lambda calls exceeded its reorder window. R28 forces
// pairing at source: aphase2 computes both bfrag sets together and issues
// A2 MFMAs alternately (cX = mfma(..); cY = mfma(..)); a3store2 packs both
// rails alternately; bphase2 interleaves the 2x4 layer-3 MFMAs + dots.
// Adjacent independent ops -> each pair hides the other's latency. Per-
// point VALU/MFMA/LDS counts UNCHANGED (R23/R24 lesson). Pre-committed
// read: null result (+-2%) with VGPR 130-155 and no spill exonerates
// chain latency -> practical structural ceiling (2 waves/SIMD register
// floor [R25], setprio null [R26], add-VALU 1:1 [R23/R24]).
// Failure signature: FETCH >> 400KB = spill -> revert to R27.
// Ledger: R22 53.5 | R23 57.1 | R24 58.7 | R25 134 (spill) | R26 54.1 |
// R27 52.0 (best).
// MFMA layouts (verified m89/m91): A[m=lane&15][k=quad*8+j],
// B[k=quad*8+j][n=lane&15], C/D row=quad*4+reg, col=lane&15.

#define NPTS (128 * 128 * 128)

typedef float f32x4_t __attribute__((ext_vector_type(4)));
typedef float f32x2_t __attribute__((ext_vector_type(2)));
typedef __fp16 g16x2_t __attribute__((ext_vector_type(2)));    // VALU half2 (cvt_pkrtz type)
typedef _Float16 h16x8_t __attribute__((ext_vector_type(8)));  // MFMA fragment

__device__ __forceinline__ unsigned h2u(g16x2_t h) {
    unsigned u;
    __builtin_memcpy(&u, &h, 4);
    return u;
}
__device__ __forceinline__ g16x2_t u2h(unsigned u) {
    g16x2_t h;
    __builtin_memcpy(&h, &u, 4);
    return h;
}

__global__ __launch_bounds__(256, 2) void mlp_kernel(
    const float* __restrict__ x,  const float* __restrict__ W1,
    const float* __restrict__ b1, const float* __restrict__ W2,
    const float* __restrict__ b2, const float* __restrict__ W3,
    const float* __restrict__ b3, const float* __restrict__ W4,
    const float* __restrict__ b4, float* __restrict__ out) {
    __shared__ __align__(16) unsigned s_basep[32][64];  // half2 {base[2c],base[2c+1]} per j
    __shared__ __align__(16) unsigned s_wcp[64];        // half2 wc pairs
    __shared__ __align__(16) float s_b2[64];
    __shared__ __align__(16) float s_b3[32];
    __shared__ __align__(16) float s_w4[32];
    // Union (45 KB): staging = w2a[16][64][8] halves (0..8191) + w3a[4][64][8]
    // (8192..10239) + W1-fold partials (floats at shorts 10240..11263, transient);
    // runtime = h2 slots [w][4][16][72] shorts (0..18431) + zf floats
    // (shorts 18432..22527 = float[4][8][16][4] : w*512 + pg7*64 + i*4 + q).
    __shared__ __align__(16) unsigned short s_u[22528];

    const int t = threadIdx.x;
    const int w = t >> 6;
    const int lane = t & 63;
    const int quad = lane >> 4;
    const int l15 = lane & 15;
    const float step = 2.0f / 127.0f;

    // ================= per-block prep, phase 1 (all 256 threads) =============
    // W1 fold partials: thread covers channel-pair p = t&63, c in [h*16,(h+1)*16)
    {
        const int p = t & 63, h = t >> 6;
        const float* r0 = W1 + (2 * p) * 67 + h * 16;
        const float* r1 = r0 + 67;
        const float* xh = x + h * 16;
        float s0 = 0.0f, s1 = 0.0f;
#pragma unroll
        for (int c = 0; c < 16; ++c) {
            const float xc = xh[c];
            s0 = fmaf(r0[c], xc, s0);
            s1 = fmaf(r1[c], xc, s1);
        }
        float2* psum = (float2*)&s_u[10240];   // [h][p], 4 x 64 float2
        psum[h * 64 + p] = make_float2(s0, s1);
    }
    // W2 [64][128] -> f16 A-frag staging (pairs along k)
    const float2* W2v = (const float2*)W2;
#pragma unroll
    for (int it = 0; it < 16; ++it) {
        int pidx = t + 256 * it;
        int idx2 = pidx * 2;
        int o = idx2 >> 7, k = idx2 & 127;
        int mt = o >> 4, lm = o & 15;
        int kb = k >> 5, q = (k >> 3) & 3, jj = k & 7;
        float2 v = W2v[pidx];
        *(unsigned*)&s_u[(mt * 4 + kb) * 512 + (q * 16 + lm) * 8 + jj] =
            h2u(__builtin_amdgcn_cvt_pkrtz(v.x, v.y));
    }
    // W3 [32][64] -> f16 A-frag staging
    const float2* W3v = (const float2*)W3;
#pragma unroll
    for (int it = 0; it < 4; ++it) {
        int pidx = t + 256 * it;
        int idx2 = pidx * 2;
        int o = idx2 >> 6, k = idx2 & 63;
        int mt = o >> 4, lm = o & 15;
        int kb = k >> 5, q = (k >> 3) & 3, jj = k & 7;
        float2 v = W3v[pidx];
        *(unsigned*)&s_u[8192 + (mt * 2 + kb) * 512 + (q * 16 + lm) * 8 + jj] =
            h2u(__builtin_amdgcn_cvt_pkrtz(v.x, v.y));
    }
    if (t < 64) s_b2[t] = b2[t];
    if (t < 32) {
        s_b3[t] = b3[t];
        s_w4[t] = W4[t];
    }
    const float bias4 = b4[0];
    __syncthreads();

    // ================= prep phase 2 (t<64): combine partials + pack tables ====
    // Block covers gi = bid>>2 (a-coord), gj0 = (bid&3)*32 (32 j-rows), all k.
    if (t < 64) {
        const float2* psum = (const float2*)&s_u[10240];
        float2 q0 = psum[t], q1 = psum[64 + t], q2 = psum[128 + t], q3 = psum[192 + t];
        float s0 = b1[2 * t] + (q0.x + q1.x) + (q2.x + q3.x);
        float s1 = b1[2 * t + 1] + (q0.y + q1.y) + (q2.y + q3.y);
        const float* r0 = W1 + (2 * t) * 67;
        const float* r1 = r0 + 67;
        const float pa = -1.0f + step * (float)(blockIdx.x >> 2);   // gi
        const float base0 = fmaf(r0[64], pa, s0);
        const float base1 = fmaf(r1[64], pa, s1);
        const float wb0 = r0[65], wb1 = r1[65];
        const int gj0 = (blockIdx.x & 3) * 32;
        s_wcp[t] = h2u(__builtin_amdgcn_cvt_pkrtz(r0[66], r1[66]));
#pragma unroll
        for (int j = 0; j < 32; ++j) {
            const float pb = -1.0f + step * (float)(gj0 + j);
            s_basep[j][t] = h2u(__builtin_amdgcn_cvt_pkrtz(
                fmaf(wb0, pb, base0), fmaf(wb1, pb, base1)));
        }
    }
    __syncthreads();

    // ================= per-wave fragment preload =================
    h16x8_t a2[16];
#pragma unroll
    for (int f = 0; f < 16; ++f) a2[f] = *(const h16x8_t*)&s_u[f * 512 + lane * 8];
    h16x8_t a3[4];
#pragma unroll
    for (int f = 0; f < 4; ++f) a3[f] = *(const h16x8_t*)&s_u[8192 + f * 512 + lane * 8];
    f32x4_t b2q[4];
#pragma unroll
    for (int mt = 0; mt < 4; ++mt) b2q[mt] = *(const f32x4_t*)&s_b2[mt * 16 + quad * 4];
    f32x4_t b3q[2];
    f32x2_t w4lo[2], w4hi[2];
#pragma unroll
    for (int mt = 0; mt < 2; ++mt) {
        b3q[mt] = *(const f32x4_t*)&s_b3[mt * 16 + quad * 4];
        float4 wq = *(const float4*)&s_w4[mt * 16 + quad * 4];
        w4lo[mt][0] = wq.x; w4lo[mt][1] = wq.y;
        w4hi[mt][0] = wq.z; w4hi[mt][1] = wq.w;
    }
    // wc pairs: loop-invariant, 16 packed regs, pinned
    unsigned twp[16];
#pragma unroll
    for (int kb = 0; kb < 4; ++kb) {
        uint4 v = *(const uint4*)&s_wcp[kb * 16 + quad * 4];
        twp[kb * 4 + 0] = v.x; twp[kb * 4 + 1] = v.y;
        twp[kb * 4 + 2] = v.z; twp[kb * 4 + 3] = v.w;
    }
#pragma unroll
    for (int i = 0; i < 16; ++i) asm volatile("" : "+v"(twp[i]));
    __syncthreads();  // union handoff: staging -> h2/zf scratch

    const int sw = (l15 & 1) * 32;                    // h2 channel swizzle (shorts)
    unsigned short* h2w = &s_u[w * 4608];             // 4 slots x 16 pts x 72 shorts
    float* zf = (float*)&s_u[18432];                  // [w][pg&7][i][q]
    const f32x2_t zero2 = {0.0f, 0.0f};
    const g16x2_t zero2h = {(__fp16)0.0f, (__fp16)0.0f};
    const int outbase = blockIdx.x * 4096 + w * 1024;

    // ---- dual-rail phase bodies: rails fused instruction-by-instruction ----
    unsigned tbp[16];
    // A-phase x2: layer 1 + layer 2 for groups pgX, pgY (alternating MFMAs)
    auto aphase2 = [&](int pgX, int pgY, f32x4_t accX[4], f32x4_t accY[4]) {
        const float pcX = fmaf(step, (float)((pgX * 16) + l15), -1.0f);
        const float pcY = fmaf(step, (float)((pgY * 16) + l15), -1.0f);
        const g16x2_t pc2X = __builtin_amdgcn_cvt_pkrtz(pcX, pcX);
        const g16x2_t pc2Y = __builtin_amdgcn_cvt_pkrtz(pcY, pcY);
        h16x8_t bfX[4], bfY[4];
#pragma unroll
        for (int kb = 0; kb < 4; ++kb) {
            union { h16x8_t v; g16x2_t h[4]; } bx, by;
#pragma unroll
            for (int p = 0; p < 4; ++p) {
                g16x2_t tw = u2h(twp[kb * 4 + p]);
                g16x2_t tb = u2h(tbp[kb * 4 + p]);
                g16x2_t hx = __builtin_elementwise_fma(tw, pc2X, tb);
                g16x2_t hy = __builtin_elementwise_fma(tw, pc2Y, tb);
                bx.h[p] = __builtin_elementwise_max(hx, zero2h);
                by.h[p] = __builtin_elementwise_max(hy, zero2h);
            }
            bfX[kb] = bx.v;
            bfY[kb] = by.v;
        }
#pragma unroll
        for (int mt = 0; mt < 4; ++mt) {
            f32x4_t cX = b2q[mt], cY = b2q[mt];
#pragma unroll
            for (int kb = 0; kb < 4; ++kb) {
                cX = __builtin_amdgcn_mfma_f32_16x16x32_f16(a2[mt * 4 + kb], bfX[kb], cX, 0, 0, 0);
                cY = __builtin_amdgcn_mfma_f32_16x16x32_f16(a2[mt * 4 + kb], bfY[kb], cY, 0, 0, 0);
            }
            accX[mt] = cX;
            accY[mt] = cY;
        }
    };
    // A3 x2: pack + relu + h2-slot writes, rails alternating
    auto a3store2 = [&](int ngX, int ngY, const f32x4_t accX[4], const f32x4_t accY[4]) {
        unsigned short* slotX = h2w + (ngX & 3) * 1152 + l15 * 72;
        unsigned short* slotY = h2w + (ngY & 3) * 1152 + l15 * 72;
#pragma unroll
        for (int mt = 0; mt < 4; ++mt) {
            g16x2_t loX = __builtin_elementwise_max(
                __builtin_amdgcn_cvt_pkrtz(accX[mt][0], accX[mt][1]), zero2h);
            g16x2_t loY = __builtin_elementwise_max(
                __builtin_amdgcn_cvt_pkrtz(accY[mt][0], accY[mt][1]), zero2h);
            g16x2_t hiX = __builtin_elementwise_max(
                __builtin_amdgcn_cvt_pkrtz(accX[mt][2], accX[mt][3]), zero2h);
            g16x2_t hiY = __builtin_elementwise_max(
                __builtin_amdgcn_cvt_pkrtz(accY[mt][2], accY[mt][3]), zero2h);
            uint2 pkX, pkY;
            pkX.x = h2u(loX); pkX.y = h2u(hiX);
            pkY.x = h2u(loY); pkY.y = h2u(hiY);
            *(uint2*)&slotX[(mt * 16 + quad * 4) ^ sw] = pkX;
            *(uint2*)&slotY[(mt * 16 + quad * 4) ^ sw] = pkY;
        }
    };
    // B-phase x2: layer 3 + w4-dot for groups pgA, pgB (alternating MFMAs)
    auto bphase2 = [&](int pgA, h16x8_t af0, h16x8_t af1,
                       int pgB, h16x8_t bf0, h16x8_t bf1) {
        f32x2_t zA = zero2, zB = zero2;
#pragma unroll
        for (int mt = 0; mt < 2; ++mt) {
            f32x4_t cA = b3q[mt], cB = b3q[mt];
            cA = __builtin_amdgcn_mfma_f32_16x16x32_f16(a3[mt * 2 + 0], af0, cA, 0, 0, 0);
            cB = __builtin_amdgcn_mfma_f32_16x16x32_f16(a3[mt * 2 + 0], bf0, cB, 0, 0, 0);
            cA = __builtin_amdgcn_mfma_f32_16x16x32_f16(a3[mt * 2 + 1], af1, cA, 0, 0, 0);
            cB = __builtin_amdgcn_mfma_f32_16x16x32_f16(a3[mt * 2 + 1], bf1, cB, 0, 0, 0);
            f32x2_t hA01 = __builtin_elementwise_max((f32x2_t){cA[0], cA[1]}, zero2);
            f32x2_t hB01 = __builtin_elementwise_max((f32x2_t){cB[0], cB[1]}, zero2);
            f32x2_t hA23 = __builtin_elementwise_max((f32x2_t){cA[2], cA[3]}, zero2);
            f32x2_t hB23 = __builtin_elementwise_max((f32x2_t){cB[2], cB[3]}, zero2);
            zA = __builtin_elementwise_fma(w4lo[mt], hA01, zA);
            zB = __builtin_elementwise_fma(w4lo[mt], hB01, zB);
            zA = __builtin_elementwise_fma(w4hi[mt], hA23, zA);
            zB = __builtin_elementwise_fma(w4hi[mt], hB23, zB);
        }
        zf[w * 512 + (pgA & 7) * 64 + l15 * 4 + quad] = zA[0] + zA[1];
        zf[w * 512 + (pgB & 7) * 64 + l15 * 4 + quad] = zB[0] + zB[1];
    };
    // phase C: batched reduce + sigmoid + coalesced store for an 8-ng batch
    auto cphase = [&](int batch) {
#pragma unroll
        for (int half = 0; half < 2; ++half) {
            const int p = lane + 64 * half;   // point within this batch's 128
            const int pg = p >> 4, i = p & 15;
            float4 v = *(const float4*)&zf[w * 512 + pg * 64 + i * 4];
            float z = (v.x + v.y) + (v.z + v.w) + bias4;
            out[outbase + batch * 128 + p] = 1.0f / (1.0f + __expf(-z));
        }
    };

    // ========== jrow-outer main loop: 8 jrows x 4 pair-iterations ==========
    // Wave w owns jrows [w*8, w*8+8); group ng = jr*8 + pg, pg in [0,8).
    // Pair-iteration handles A(2i),A(2i+1) and B(2i-2),B(2i-1).
    for (int jr = 0; jr < 8; ++jr) {
        // base pairs for this jrow: 16 packed regs, pinned
        const unsigned* bp = &s_basep[w * 8 + jr][0];
#pragma unroll
        for (int kb = 0; kb < 4; ++kb) {
            uint4 v = *(const uint4*)&bp[kb * 16 + quad * 4];
            tbp[kb * 4 + 0] = v.x; tbp[kb * 4 + 1] = v.y;
            tbp[kb * 4 + 2] = v.z; tbp[kb * 4 + 3] = v.w;
        }
#pragma unroll
        for (int i = 0; i < 16; ++i) asm volatile("" : "+v"(tbp[i]));

#pragma unroll 2
        for (int pgp = 0; pgp < 4; ++pgp) {
            const int pgX = 2 * pgp, pgY = pgX + 1;
            const int ngX = jr * 8 + pgX, ngY = ngX + 1;
            // ---- prefetch b3f fragments for bphase(ngX-2), bphase(ngY-2) ----
            h16x8_t bxf0, bxf1, byf0, byf1;
            if (ngX > 1) {
                const unsigned short* ps0 = h2w + ((ngX - 2) & 3) * 1152 + l15 * 72;
                bxf0 = *(const h16x8_t*)&ps0[(0 ^ sw) + quad * 8];
                bxf1 = *(const h16x8_t*)&ps0[(32 ^ sw) + quad * 8];
                const unsigned short* ps1 = h2w + ((ngY - 2) & 3) * 1152 + l15 * 72;
                byf0 = *(const h16x8_t*)&ps1[(0 ^ sw) + quad * 8];
                byf1 = *(const h16x8_t*)&ps1[(32 ^ sw) + quad * 8];
            }
            // ---- fused dual-rail A-phase (alternating independent MFMAs) ----
            f32x4_t accX[4], accY[4];
            aphase2(pgX, pgY, accX, accY);
            a3store2(ngX, ngY, accX, accY);
            // ---- fused dual-rail B-phase for the previous pair ----
            if (ngX > 1) {
                bphase2(ngX - 2, bxf0, bxf1, ngY - 2, byf0, byf1);
                if (((ngY - 2) & 7) == 7) cphase((ngY - 2) >> 3);
            }
        }
    }
    {   // drain: groups 62, 63 + final batch
        const unsigned short* ps0 = h2w + (62 & 3) * 1152 + l15 * 72;
        h16x8_t bxf0 = *(const h16x8_t*)&ps0[(0 ^ sw) + quad * 8];
        h16x8_t bxf1 = *(const h16x8_t*)&ps0[(32 ^ sw) + quad * 8];
        const unsigned short* ps1 = h2w + (63 & 3) * 1152 + l15 * 72;
        h16x8_t byf0 = *(const h16x8_t*)&ps1[(0 ^ sw) + quad * 8];
        h16x8_t byf1 = *(const h16x8_t*)&ps1[(32 ^ sw) + quad * 8];
        bphase2(62, bxf0, bxf1, 63, byf0, byf1);
        cphase(7);
    }
}

extern "C" void kernel_launch(void* const* d_in, const int* in_sizes, int n_in,
                              void* d_out, int out_size, void* d_ws, size_t ws_size,
                              hipStream_t stream) {
    mlp_kernel<<<NPTS / 4096, 256, 0, stream>>>(
        (const float*)d_in[0], (const float*)d_in[1], (const float*)d_in[2],
        (const float*)d_in[3], (const float*)d_in[4], (const float*)d_in[5],
        (const float*)d_in[6], (const float*)d_in[7], (const float*)d_in[8],
        (float*)d_out);
}